// Round 7
// baseline (3899.009 us; speedup 1.0000x reference)
//
#include <hip/hip_runtime.h>
#include <hip/hip_bf16.h>
#include <stdint.h>

#define BATCH 1024
#define DIM   1024
#define HID   4096
#define TPTS  16
#define NBLK  512   // 2 blocks/CU x 256 CUs, co-resident (proven by R8 run)

typedef __attribute__((ext_vector_type(8))) short  short8;
typedef __attribute__((ext_vector_type(4))) float  floatx4;
typedef __attribute__((ext_vector_type(4))) unsigned int uint32x4;

__device__ __forceinline__ unsigned short f32_to_bf16_bits(float f) {
    union { float f; unsigned u; } v; v.f = f;
    return (unsigned short)((v.u + 0x7fffu + ((v.u >> 16) & 1u)) >> 16);
}

__device__ __forceinline__ void store_bf16x4(unsigned short* p, floatx4 v) {
    union { unsigned short u[4]; uint2 q; } pk;
    pk.u[0] = f32_to_bf16_bits(v[0]);
    pk.u[1] = f32_to_bf16_bits(v[1]);
    pk.u[2] = f32_to_bf16_bits(v[2]);
    pk.u[3] = f32_to_bf16_bits(v[3]);
    *(uint2*)p = pk.q;
}

// bf16x4 pack + write-THROUGH store (sc0 sc1): data lands at the coherence
// point, nothing dirty in any L2. R6-validated. Fire-and-forget — cheap.
__device__ __forceinline__ void st_sys_bf16x4(unsigned short* p, floatx4 v) {
    union { unsigned short u[4]; unsigned long long q; } pk;
    pk.u[0] = f32_to_bf16_bits(v[0]);
    pk.u[1] = f32_to_bf16_bits(v[1]);
    pk.u[2] = f32_to_bf16_bits(v[2]);
    pk.u[3] = f32_to_bf16_bits(v[3]);
    __hip_atomic_store((unsigned long long*)p, pk.q,
                       __ATOMIC_RELAXED, __HIP_MEMORY_SCOPE_SYSTEM);
}

// 16B write-through store: NOT an atomic op — a normal global_store_dwordx4
// with sc0 sc1 cache policy -> full store throughput (R8's lesson: never put
// 8B atomic ops on a bulk path).
__device__ __forceinline__ void st_sys16(void* p, uint32x4 v) {
    asm volatile("global_store_dwordx4 %0, %1, off sc0 sc1"
                 :: "v"((unsigned long long)(uintptr_t)p), "v"(v) : "memory");
}

// fast tanh: 1 - 2/(e^{2x}+1); saturates correctly for |x| large
__device__ __forceinline__ float fast_tanh(float x) {
    float e = __expf(2.0f * x);
    return 1.0f - 2.0f / (e + 1.0f);
}

// async 16B global -> LDS DMA. LDS dest = wave-uniform base + lane*16.
__device__ __forceinline__ void g2l16(const unsigned short* g, char* l) {
    __builtin_amdgcn_global_load_lds(
        (const __attribute__((address_space(1))) void*)g,
        (__attribute__((address_space(3))) void*)l, 16, 0, 0);
}

// Fence-free counter barrier. __syncthreads drains this block's stores
// (s_waitcnt vmcnt(0) before s_barrier) -> write-through stores are at the
// coherence point before tid0 arrives. NO fence instructions (R5/R7: any
// buffer_wbl2/inv in the hot path = disaster). Monotonic counter; targets
// passed from host; init zeroes it each launch/replay.
__device__ __forceinline__ void ctrbar(unsigned* bar, unsigned tgt) {
    __syncthreads();
    if (threadIdx.x == 0) {
        __hip_atomic_fetch_add(bar, 1u, __ATOMIC_RELAXED,
                               __HIP_MEMORY_SCOPE_AGENT);
        while (__hip_atomic_load(bar, __ATOMIC_RELAXED,
                                 __HIP_MEMORY_SCOPE_AGENT) < tgt)
            __builtin_amdgcn_s_sleep(2);
    }
    __syncthreads();
    asm volatile("" ::: "memory");
}

// R3's measured-best gemm core (64x128 tile, BK=64, 4 waves of 64x32, 2-phase
// double-buffered 2x24KB LDS, ~920 TF at 2 blocks/CU). A row-major bf16 (lda),
// Bt = B^T row-major (ldb). PLAIN DMA staging — safe for intra-dispatch
// producer->consumer because producers store write-through (sc0 sc1) and the
// reader's L1/L2 were invalidated at dispatch start and never touched these
// lines before the barrier (same mechanism R3 relies on across dispatches).
__device__ __forceinline__ void gemm_tile(
    const unsigned short* A, const unsigned short* Bt,
    int lda, int ldb, int rowBase, int colBase, long long koff,
    char* smem, floatx4 (&acc)[4][2])
{
    const int tid  = threadIdx.x;
    const int wave = tid >> 6;
    const int lane = tid & 63;
    const int wn = wave * 32;
    const int lr = lane & 15;
    const int q  = lane >> 4;

    // staging: 24KB / (256 thr * 16B) = 6 calls; j=0..1 -> sA, j=2..5 -> sB
    // Row = 8 chunks of 16B; chunk ch holds global k-chunk ch ^ (row & 7).
    const unsigned short* gp[6];
    int lo[6];
#pragma unroll
    for (int j = 0; j < 6; ++j) {
        const int p  = (j * 256 + tid) * 16;
        const int pa = (j < 2) ? p : (p - 8192);
        const int row = pa >> 7;
        const int ch  = (pa >> 4) & 7;
        const int sc  = ch ^ (row & 7);
        if (j < 2)
            gp[j] = A + (long long)(rowBase + row) * lda + koff + sc * 8;
        else
            gp[j] = Bt + (long long)(colBase + row) * ldb + koff + sc * 8;
        lo[j] = p;
    }

#pragma unroll
    for (int mi = 0; mi < 4; ++mi)
#pragma unroll
        for (int ni = 0; ni < 2; ++ni) {
            floatx4 z4 = {0.f, 0.f, 0.f, 0.f};
            acc[mi][ni] = z4;
        }

    const int xr = lr & 7;
    int aOff[4], bOff[2];
#pragma unroll
    for (int i = 0; i < 4; ++i) aOff[i] = (i * 16 + lr) * 128;
#pragma unroll
    for (int i = 0; i < 2; ++i) bOff[i] = (wn + i * 16 + lr) * 128;
    const int swz0 = ((0 + q) ^ xr) * 16;
    const int swz1 = ((4 + q) ^ xr) * 16;

    // prologue: stage K-tile 0 into buffer 0
#pragma unroll
    for (int j = 0; j < 6; ++j)
        g2l16(gp[j], smem + lo[j]);
    __syncthreads();

    int cur = 0;
    for (int kb = 0; kb < 16; ++kb) {        // K = 1024, BK = 64
        if (kb + 1 < 16) {                   // issue next tile's loads first
            const int kadv = (kb + 1) * 64;
            char* nb = smem + (cur ^ 1) * 24576;
#pragma unroll
            for (int j = 0; j < 6; ++j)
                g2l16(gp[j] + kadv, nb + lo[j]);
        }
        const char* sAb = smem + cur * 24576;
        const char* sBb = sAb + 8192;

        short8 af[4][2], bfr[2][2];
#pragma unroll
        for (int i = 0; i < 4; ++i) {
            af[i][0] = *(const short8*)(sAb + aOff[i] + swz0);
            af[i][1] = *(const short8*)(sAb + aOff[i] + swz1);
        }
#pragma unroll
        for (int i = 0; i < 2; ++i) {
            bfr[i][0] = *(const short8*)(sBb + bOff[i] + swz0);
            bfr[i][1] = *(const short8*)(sBb + bOff[i] + swz1);
        }
#pragma unroll
        for (int g = 0; g < 2; ++g)
#pragma unroll
            for (int mi = 0; mi < 4; ++mi)
#pragma unroll
                for (int ni = 0; ni < 2; ++ni)
                    acc[mi][ni] = __builtin_amdgcn_mfma_f32_16x16x32_bf16(
                        af[mi][g], bfr[ni][g], acc[mi][ni], 0, 0, 0);

        __syncthreads();   // drains next tile's DMA + protects buffer cur
        cur ^= 1;
    }
}

// ============================================================================
// eval_fused: ONE dispatch per vf-eval:
//   phase A (cmode!=0): combine for the PREVIOUS eval (verbatim math,
//     bitwise-identical). Ybf written via 8B write-through stores.
//     -> ctrbar(tgt1)
//   phase B: gemm1 (A=Ybf plain DMA). Epilogue writes Hbf via 16B
//     write-through stores.   -> ctrbar(tgt2)
//   phase C: gemm2 split-K (A=Hbf plain DMA), parts stored plain (consumed
//     by the NEXT dispatch -> runtime boundary coherence, as in R3).
// Anti-race: phase A reads parts(prev eval); no block reaches phase C (which
// overwrites parts) until ALL blocks passed both barriers, i.e. finished
// phase A. Ybf write(A)/read(B) and Hbf write(B)/read(C) are barrier-split.
// ============================================================================
__global__ __launch_bounds__(256, 2)
void eval_fused(const unsigned short* __restrict__ W1T,
                const unsigned short* __restrict__ W2T,
                const float* __restrict__ b1,
                const float* __restrict__ b2,
                const float* __restrict__ tspan,
                unsigned short* __restrict__ Ybf,
                unsigned short* __restrict__ Hbf,
                float* __restrict__ parts,
                float* __restrict__ kacc,
                float* __restrict__ traj,
                unsigned* __restrict__ bar,
                unsigned tgt1, unsigned tgt2, int cstep, int cmode)
{
    __shared__ __align__(16) char smem[49152];
    const int tid = threadIdx.x;
    const int bid = (int)blockIdx.x;
    const int wave = tid >> 6;
    const int wn = wave * 32;
    const int lr = (tid & 63) & 15;
    const int q  = (tid & 63) >> 4;

    // ---------------- phase A: combine for previous eval --------------------
    if (cmode) {
        const float h = tspan[cstep + 1] - tspan[cstep];
        const floatx4* pp = (const floatx4*)parts;
        const floatx4* yc = (const floatx4*)(traj + (long long)cstep * BATCH * DIM);
        floatx4* yn = (floatx4*)(traj + (long long)(cstep + 1) * BATCH * DIM);
        floatx4* ka = (floatx4*)kacc;
        const int NV4 = BATCH * DIM / 4;
#pragma unroll
        for (int u = 0; u < 2; ++u) {
            const int i = (bid << 9) + tid * 2 + u;   // 512 f4 per block
            // EXACT combine order: p0+p1+p2+p3, then +b2 (bitwise identical)
            floatx4 k = pp[i] + pp[i + NV4] + pp[i + 2 * NV4] + pp[i + 3 * NV4];
            k = k + *(const floatx4*)(b2 + ((i * 4) & (DIM - 1)));
            floatx4 y = yc[i];
            floatx4 ynew;
            if (cmode == 1)      { ka[i] = k;                ynew = y + (0.5f * h) * k; }
            else if (cmode == 2) { ka[i] = ka[i] + 2.0f * k; ynew = y + (0.5f * h) * k; }
            else if (cmode == 3) { ka[i] = ka[i] + 2.0f * k; ynew = y + h * k; }
            else { ynew = y + (h * (1.0f / 6.0f)) * (ka[i] + k); yn[i] = ynew; }
            st_sys_bf16x4(Ybf + i * 4, ynew);   // write-through, no fence
        }
        ctrbar(bar, tgt1);
    }

    // XCD-chunked bijective swizzle (perf-only; 512 % 8 == 0), shared by both
    // gemm phases: swz enumerates 64 consecutive tiles per XCD.
    const int swz = ((bid & 7) << 6) | (bid >> 3);
    // phase-B tile (grid 32x16): XCD k -> col-groups 4k..4k+3, all 16 row-grps
    const int cb1 = (swz >> 4) << 7;
    const int rb1 = (swz & 15) << 6;
    // phase-C tile (grid 8x16x4): XCD pair {2z,2z+1} -> K-slice z
    const int z2  = swz >> 7;
    const int tl2 = swz & 127;
    const int cb2 = (tl2 & 7) << 7;
    const int rb2 = (tl2 >> 3) << 6;

    floatx4 acc[4][2];

    // ---------------- phase B: H = bf16(tanh(Y @ W1 + b1)) ------------------
    gemm_tile(Ybf, W1T, DIM, DIM, rb1, cb1, 0LL, smem, acc);
    {
        float bias2[2];
#pragma unroll
        for (int ni = 0; ni < 2; ++ni)
            bias2[ni] = b1[cb1 + wn + ni * 16 + lr];
        unsigned short* sC = (unsigned short*)smem;  // [64][136] bf16
#pragma unroll
        for (int mi = 0; mi < 4; ++mi)
#pragma unroll
            for (int ni = 0; ni < 2; ++ni)
#pragma unroll
                for (int r = 0; r < 4; ++r) {
                    const int row = mi * 16 + q * 4 + r;
                    const int col = wn + ni * 16 + lr;
                    sC[row * 136 + col] = f32_to_bf16_bits(
                        fast_tanh(acc[mi][ni][r] + bias2[ni]));
                }
        __syncthreads();
#pragma unroll
        for (int it = 0; it < 4; ++it) {
            const int row = it * 16 + (tid >> 4);
            const int cc  = (tid & 15) * 8;
            st_sys16(Hbf + (long long)(rb1 + row) * HID + cb1 + cc,
                     *(const uint32x4*)(sC + row * 136 + cc));
        }
    }
    ctrbar(bar, tgt2);

    // ---------------- phase C: parts[z] = H[:,z*1024:+1024] @ W2-slice ------
    gemm_tile(Hbf, W2T, HID, HID, rb2, cb2, (long long)z2 * 1024, smem, acc);
    {
        float* C = parts + (long long)z2 * (BATCH * DIM);
#pragma unroll
        for (int mi = 0; mi < 4; ++mi)
#pragma unroll
            for (int ni = 0; ni < 2; ++ni) {
                const int r0 = rb2 + mi * 16 + q * 4;
                const int c  = cb2 + wn + ni * 16 + lr;
#pragma unroll
                for (int r = 0; r < 4; ++r)
                    C[(long long)(r0 + r) * DIM + c] = acc[mi][ni][r];
            }
    }
}

// standalone combine — used once for the FINAL eval (step 14, mode 4).
__global__ void combine_final(const float* __restrict__ parts,
                              const float* __restrict__ b2,
                              const float* __restrict__ ycur,
                              const float* __restrict__ tspan,
                              float* __restrict__ kacc,
                              float* __restrict__ ynext)
{
    const int i = blockIdx.x * blockDim.x + threadIdx.x;
    const float h = tspan[15] - tspan[14];
    const int NV = BATCH * DIM / 4;
    const floatx4* p = (const floatx4*)parts;
    floatx4 k = p[i] + p[i + NV] + p[i + 2 * NV] + p[i + 3 * NV];
    k = k + *(const floatx4*)(b2 + ((i * 4) & (DIM - 1)));
    floatx4 y = ((const floatx4*)ycur)[i];
    floatx4* ka = (floatx4*)kacc;
    floatx4 yn = y + (h * (1.0f / 6.0f)) * (ka[i] + k);
    ((floatx4*)ynext)[i] = yn;
}

// out[c][r] = bf16(in[r][c]); in is R x C fp32.
__global__ void transpose_cast(const float* __restrict__ in,
                               unsigned short* __restrict__ out, int R, int C)
{
    __shared__ float tile[32][33];
    const int bx = blockIdx.x * 32;
    const int by = blockIdx.y * 32;
    const int tx = threadIdx.x, ty = threadIdx.y;  // (32, 8)
#pragma unroll
    for (int i = 0; i < 4; ++i)
        tile[ty + i * 8][tx] = in[(long long)(by + ty + i * 8) * C + bx + tx];
    __syncthreads();
#pragma unroll
    for (int i = 0; i < 4; ++i)
        out[(long long)(bx + ty + i * 8) * R + by + tx] =
            f32_to_bf16_bits(tile[tx][ty + i * 8]);
}

// d_out[0:16] = t_span; traj[0] = y_init; ybf = bf16(y_init); zero barrier ctr
__global__ void init_kernel(const float* __restrict__ y0,
                            const float* __restrict__ tspan,
                            float* __restrict__ out,
                            unsigned short* __restrict__ ybf,
                            unsigned int* __restrict__ bar)
{
    const int i = blockIdx.x * blockDim.x + threadIdx.x;
    floatx4 v = ((const floatx4*)y0)[i];
    ((floatx4*)(out + TPTS))[i] = v;
    store_bf16x4(ybf + i * 4, v);
    if (blockIdx.x == 0 && threadIdx.x < TPTS) out[threadIdx.x] = tspan[threadIdx.x];
    if (blockIdx.x == 1 && threadIdx.x == 0) *bar = 0u;
}

extern "C" void kernel_launch(void* const* d_in, const int* in_sizes, int n_in,
                              void* d_out, int out_size, void* d_ws, size_t ws_size,
                              hipStream_t stream)
{
    (void)in_sizes; (void)n_in; (void)out_size; (void)ws_size;
    const float* y0    = (const float*)d_in[0];
    const float* tspan = (const float*)d_in[1];
    const float* W1    = (const float*)d_in[2];
    const float* b1    = (const float*)d_in[3];
    const float* W2    = (const float*)d_in[4];
    const float* b2    = (const float*)d_in[5];
    float* out = (float*)d_out;

    char* ws = (char*)d_ws;
    unsigned short* W1T = (unsigned short*)(ws);                // [HID][DIM] bf16   8MB
    unsigned short* W2T = (unsigned short*)(ws + (8ll << 20));  // [DIM][HID] bf16   8MB
    unsigned short* Ybf = (unsigned short*)(ws + (16ll << 20)); // [BATCH][DIM] bf16 2MB
    unsigned short* Hbf = (unsigned short*)(ws + (18ll << 20)); // [BATCH][HID] bf16 8MB
    float* parts = (float*)(ws + (26ll << 20));                 // [4][BATCH][DIM]  16MB
    float* kacc  = (float*)(ws + (42ll << 20));                 // [BATCH][DIM]      4MB
    unsigned int* bar = (unsigned int*)(ws + (46ll << 20));     // barrier counter

    dim3 tb(32, 8);
    transpose_cast<<<dim3(HID / 32, DIM / 32), tb, 0, stream>>>(W1, W1T, DIM, HID);
    transpose_cast<<<dim3(DIM / 32, HID / 32), tb, 0, stream>>>(W2, W2T, HID, DIM);
    init_kernel<<<BATCH * DIM / 1024, 256, 0, stream>>>(y0, tspan, out, Ybf, bar);

    float* traj = out + TPTS;
    unsigned base = 0;
    for (int k = 0; k < 60; ++k) {          // 60 vf-evals; eval k's combine
        const int cmode = (k == 0) ? 0 : ((k - 1) & 3) + 1;  // runs in launch k+1
        const int cstep = (k == 0) ? 0 : (k - 1) >> 2;
        unsigned tgt1, tgt2;
        if (cmode) { tgt1 = base + NBLK; tgt2 = base + 2 * NBLK; base += 2 * NBLK; }
        else       { tgt1 = 0;           tgt2 = base + NBLK;     base += NBLK; }
        eval_fused<<<NBLK, 256, 0, stream>>>(W1T, W2T, b1, b2, tspan,
                                             Ybf, Hbf, parts, kacc, traj, bar,
                                             tgt1, tgt2, cstep, cmode);
    }
    // final eval's combine (step 14, mode 4) -> traj[15]
    combine_final<<<BATCH * DIM / 1024, 256, 0, stream>>>(
        parts, b2, traj + 14LL * BATCH * DIM, tspan, kacc,
        traj + 15LL * BATCH * DIM);
}